// Round 1
// baseline (5696.918 us; speedup 1.0000x reference)
//
#include <hip/hip_runtime.h>
#include <cmath>

// ---------------------------------------------------------------------------
// RPN head on MI355X. fp32 throughout (order-sensitive output: top-k ranks and
// greedy-NMS decisions must match the fp32 reference; bf16 MFMA would perturb
// scores ~2e-4 >> the ~2e-5 rank gap at the level-0 top-1000 boundary).
// Pipeline:
//   1. wtrans:      W[oc][ic][3][3] -> Wt[k=ic*9+t][oc]   (coalesced staging)
//   2. conv_fused:  3x3 conv + bias + relu, fused 1x1 cls/bbox heads + anchor
//                   decode + clip -> scores[N], boxes[N][4] per level/image
//   3. topk_kernel<false>: exact lax.top_k (value desc, index asc ties) via
//                   radix-select + tie bisection + bitonic sort of packed keys
//   4. nms_matrix:  1000x1000 suppression bitmask per (level,image)
//   5. nms_scan:    sequential greedy scan (1 wave/task), filtered scores
//   6. topk_kernel<true>: global top-1000 over 4768, writes [B,1000,5]
// ---------------------------------------------------------------------------

#define NTOT_PER_IMG 261888   // sum of H*W*3 over levels
#define ATOT_PER_IMG 4768     // 4*1000 + 768

__constant__ int c_NLVL[5] = {196608, 49152, 12288, 3072, 768};
__constant__ int c_KLVL[5] = {1000, 1000, 1000, 1000, 768};
__constant__ int c_LOFF[5] = {0, 196608, 245760, 258048, 261120};
__constant__ int c_AOFF[5] = {0, 1000, 2000, 3000, 4000};

struct Anch { float cx1[3]; float cy1[3]; };

// ------------------------------ weight transpose ---------------------------
__global__ __launch_bounds__(256) void wtrans(const float* __restrict__ Wsrc,
                                              float* __restrict__ Wt) {
  __shared__ float T[16][17];
  int k0 = blockIdx.x * 16;   // 2304/16 = 144
  int o0 = blockIdx.y * 16;   // 256/16  = 16
  int i = threadIdx.x >> 4, j = threadIdx.x & 15;
  T[i][j] = Wsrc[(size_t)(o0 + i) * 2304 + (k0 + j)];
  __syncthreads();
  Wt[(size_t)(k0 + i) * 256 + (o0 + j)] = T[j][i];
}

// ------------------------------ fused conv ---------------------------------
// Block: 256 threads; tile = PT pixels (one row segment) x 256 out-channels.
// Thread (tx=tid&15, ty=tid>>4): oc = ty*16+i (i<16), px = x0+tx*TP+p (p<TP).
template <int PT, int TP>
__global__ __launch_bounds__(256) void conv_fused(
    const float* __restrict__ feat, const float* __restrict__ Wt,
    const float* __restrict__ convb, const float* __restrict__ clsw,
    const float* __restrict__ clsb, const float* __restrict__ bboxw,
    const float* __restrict__ bboxb, float* __restrict__ scoresOut,
    float4* __restrict__ boxesOut, int H, int stride, int lvlOff, Anch an) {
  static_assert(PT == TP * 16, "tile");
  constexpr int XS = PT + 4;           // padded LDS row stride
  constexpr int XSZ = 4 * 3 * XS;
  __shared__ __align__(16) float sm[9216 + XSZ + 3840 + 256 + 16 + 272];
  float* Ws = sm;               // [36][256] staged weights (chunk of 4 ic)
  float* Xs = sm + 9216;        // [4][3][XS] staged input rows
  float* CW = Xs + XSZ;         // [15][256] cls(3)+bbox(12) weights
  float* Cb = CW + 3840;        // [256] conv bias
  float* Bb = Cb + 256;         // [15] cls/bbox bias
  float* Red2 = Bb + 16;        // [16][17] reduced head values per pixel
  float* Red = sm;              // epilogue scratch, aliases Ws (4096 <= 9216)

  const int tid = threadIdx.x;
  const int tx = tid & 15;
  const int ty = tid >> 4;
  const int W = H;
  const int x0 = blockIdx.x * PT;
  const int gy = blockIdx.y;
  const int img = blockIdx.z;
  const float* f = feat + (size_t)img * 256 * H * W;

  for (int i = tid; i < 15 * 256; i += 256)
    CW[i] = (i < 768) ? clsw[i] : bboxw[i - 768];
  Cb[tid] = convb[tid];
  if (tid < 15) Bb[tid] = (tid < 3) ? clsb[tid] : bboxb[tid - 3];

  float acc[16][TP];
#pragma unroll
  for (int i = 0; i < 16; i++)
#pragma unroll
    for (int p = 0; p < TP; p++) acc[i][p] = 0.f;

  for (int ic0 = 0; ic0 < 256; ic0 += 4) {
    __syncthreads();  // protect Ws/Xs from previous chunk's readers
    // stage weights: 36 rows x 256, flat copy (coalesced float4)
    {
      const float4* wsrc = (const float4*)(Wt + (size_t)ic0 * 9 * 256);
      float4* wdst = (float4*)Ws;
#pragma unroll
      for (int i = 0; i < 9; i++) wdst[tid + i * 256] = wsrc[tid + i * 256];
    }
    // stage input rows (with halo, zero-padded)
    for (int idx = tid; idx < 4 * 3 * (PT + 2); idx += 256) {
      int icr = idx / (3 * (PT + 2));
      int rem = idx - icr * 3 * (PT + 2);
      int ry = rem / (PT + 2);
      int xi = rem - ry * (PT + 2);
      int yy = gy + ry - 1;
      int xx = x0 + xi - 1;
      float v = 0.f;
      if (yy >= 0 && yy < H && xx >= 0 && xx < W)
        v = f[(size_t)(ic0 + icr) * H * W + (size_t)yy * W + xx];
      Xs[(icr * 3 + ry) * XS + xi] = v;
    }
    __syncthreads();
    for (int icr = 0; icr < 4; icr++) {
#pragma unroll
      for (int ky = 0; ky < 3; ky++) {
        float xv[TP + 2];
        const float* xrow = &Xs[(icr * 3 + ky) * XS + tx * TP];
#pragma unroll
        for (int q = 0; q < TP + 2; q++) xv[q] = xrow[q];
#pragma unroll
        for (int kx = 0; kx < 3; kx++) {
          const float* wr = &Ws[(icr * 9 + ky * 3 + kx) * 256 + ty * 16];
          float wv[16];
#pragma unroll
          for (int i4 = 0; i4 < 4; i4++) {
            float4 w4 = *(const float4*)(wr + i4 * 4);
            wv[i4 * 4] = w4.x; wv[i4 * 4 + 1] = w4.y;
            wv[i4 * 4 + 2] = w4.z; wv[i4 * 4 + 3] = w4.w;
          }
#pragma unroll
          for (int i = 0; i < 16; i++)
#pragma unroll
            for (int p = 0; p < TP; p++)
              acc[i][p] = __builtin_fmaf(wv[i], xv[p + kx], acc[i][p]);
        }
      }
    }
  }
  __syncthreads();

  const float BCLIP = (float)4.135166556742356;  // log(1000/16)
  const size_t base = (size_t)img * NTOT_PER_IMG + lvlOff;

  for (int p = 0; p < TP; p++) {
    // relu(t) and 15 per-oc-group partial dot products
    float tv[16];
#pragma unroll
    for (int i = 0; i < 16; i++)
      tv[i] = fmaxf(acc[i][p] + Cb[ty * 16 + i], 0.f);
#pragma unroll
    for (int c = 0; c < 15; c++) {
      const float* wr = &CW[c * 256 + ty * 16];
      float s = 0.f;
#pragma unroll
      for (int i = 0; i < 16; i++) s += wr[i] * tv[i];
      Red[(tx * 16 + c) * 16 + ty] = s;
    }
    __syncthreads();
    if (tid < 240) {  // reduce across the 16 ty groups
      int px = tid / 15, c = tid - px * 15;
      const float* rr = &Red[(px * 16 + c) * 16];
      float s = 0.f;
#pragma unroll
      for (int t = 0; t < 16; t++) s += rr[t];
      Red2[px * 17 + c] = s + Bb[c];
    }
    __syncthreads();
    if (tid < 48) {  // decode: one (pixel, anchor) per thread
      int px = tid / 3, a = tid - px * 3;
      int gx = x0 + px * TP + p;
      float sc = Red2[px * 17 + a];
      float dxv = Red2[px * 17 + 3 + a * 4 + 0];
      float dyv = Red2[px * 17 + 3 + a * 4 + 1];
      float dwv = Red2[px * 17 + 3 + a * 4 + 2];
      float dhv = Red2[px * 17 + 3 + a * 4 + 3];
      float sx = (float)(gx * stride), sy = (float)(gy * stride);
      float x1 = __fadd_rn(sx, an.cx1[a]);
      float x2 = __fsub_rn(sx, an.cx1[a]);
      float y1 = __fadd_rn(sy, an.cy1[a]);
      float y2 = __fsub_rn(sy, an.cy1[a]);
      float wdt = __fadd_rn(__fsub_rn(x2, x1), 1.0f);
      float hgt = __fadd_rn(__fsub_rn(y2, y1), 1.0f);
      float ctx = __fadd_rn(x1, __fmul_rn(0.5f, wdt));
      float cty = __fadd_rn(y1, __fmul_rn(0.5f, hgt));
      float dw = fminf(dwv, BCLIP), dh = fminf(dhv, BCLIP);
      float pcx = __fadd_rn(__fmul_rn(dxv, wdt), ctx);
      float pcy = __fadd_rn(__fmul_rn(dyv, hgt), cty);
      float pw = __fmul_rn(expf(dw), wdt);
      float ph = __fmul_rn(expf(dh), hgt);
      float hw = __fmul_rn(0.5f, pw), hh = __fmul_rn(0.5f, ph);
      float bx1 = __fsub_rn(pcx, hw);
      float by1 = __fsub_rn(pcy, hh);
      float bx2 = __fsub_rn(__fadd_rn(pcx, hw), 1.0f);
      float by2 = __fsub_rn(__fadd_rn(pcy, hh), 1.0f);
      bx1 = fminf(fmaxf(bx1, 0.f), 1023.f);
      by1 = fminf(fmaxf(by1, 0.f), 1023.f);
      bx2 = fminf(fmaxf(bx2, 0.f), 1023.f);
      by2 = fminf(fmaxf(by2, 0.f), 1023.f);
      int g = gy * W + gx;
      size_t o = base + (size_t)g * 3 + a;
      scoresOut[o] = sc;
      boxesOut[o] = make_float4(bx1, by1, bx2, by2);
    }
    __syncthreads();
  }
}

// ------------------------------ top-k --------------------------------------
__device__ __forceinline__ unsigned fkey(float f) {
  unsigned b = __float_as_uint(f);
  return (b & 0x80000000u) ? ~b : (b | 0x80000000u);
}
__device__ __forceinline__ float funkey(unsigned u) {
  unsigned b = (u & 0x80000000u) ? (u & 0x7fffffffu) : ~u;
  return __uint_as_float(b);
}

// Exact lax.top_k: value desc, index asc on ties. Radix-select the threshold,
// bisect an index cut for boundary ties, bitonic-sort packed (key, ~idx).
template <bool FINAL>
__global__ __launch_bounds__(1024) void topk_kernel(
    const float* __restrict__ scoresIn, const float4* __restrict__ boxesIn,
    float* __restrict__ scoresOut, float4* __restrict__ boxesOut,
    float* __restrict__ finalOut) {
  __shared__ unsigned long long keys[1024];
  __shared__ unsigned hist[256];
  __shared__ unsigned s_comm[4];
  int lvl = 0, img, N, k;
  const float* src;
  const float4* bsrc;
  if (FINAL) {
    img = blockIdx.x; N = ATOT_PER_IMG; k = 1000;
    src = scoresIn + (size_t)img * ATOT_PER_IMG;
    bsrc = boxesIn + (size_t)img * ATOT_PER_IMG;
  } else {
    lvl = blockIdx.x; img = blockIdx.y;
    N = c_NLVL[lvl]; k = c_KLVL[lvl];
    src = scoresIn + (size_t)img * NTOT_PER_IMG + c_LOFF[lvl];
    bsrc = boxesIn + (size_t)img * NTOT_PER_IMG + c_LOFF[lvl];
  }
  const int tid = threadIdx.x;

  unsigned pref = 0, pmask = 0, krem = (unsigned)k, cntT = 0;
  for (int pass = 3; pass >= 0; pass--) {
    int shift = pass * 8;
    if (tid < 256) hist[tid] = 0;
    __syncthreads();
    for (int i = tid; i < N; i += 1024) {
      unsigned u = fkey(src[i]);
      if ((u & pmask) == pref) atomicAdd(&hist[(u >> shift) & 255], 1u);
    }
    __syncthreads();
    if (tid == 0) {
      unsigned cum = 0;
      for (int d = 255; d >= 0; d--) {
        unsigned c = hist[d];
        if (cum + c >= krem) {
          s_comm[0] = krem - cum; s_comm[1] = c; s_comm[2] = (unsigned)d;
          break;
        }
        cum += c;
      }
    }
    __syncthreads();
    krem = s_comm[0]; cntT = s_comm[1];
    pref |= s_comm[2] << shift;
    pmask |= 0xFFu << shift;
    __syncthreads();
  }
  const unsigned T = pref, r = krem;
  unsigned m = (unsigned)N;
  if (r < cntT) {  // boundary ties: smallest r indices among {u == T}
    unsigned lo = 0, hi = (unsigned)N;
    while (lo < hi) {
      unsigned mid = (lo + hi) >> 1;
      if (tid == 0) s_comm[3] = 0;
      __syncthreads();
      for (unsigned i = tid; i < mid; i += 1024)
        if (fkey(src[i]) == T) atomicAdd(&s_comm[3], 1u);
      __syncthreads();
      unsigned c = s_comm[3];
      __syncthreads();
      if (c >= r) hi = mid; else lo = mid + 1;
    }
    m = lo;
  }
  if (tid == 0) s_comm[3] = 0;
  __syncthreads();
  for (int i = tid; i < N; i += 1024) {
    unsigned u = fkey(src[i]);
    if (u > T || (u == T && (unsigned)i < m)) {
      unsigned p = atomicAdd(&s_comm[3], 1u);
      if (p < 1024)
        keys[p] = ((unsigned long long)u << 32) | (unsigned)(~(unsigned)i);
    }
  }
  __syncthreads();
  if (tid >= k) keys[tid] = 0ull;  // pad; sorts to the end
  __syncthreads();
  // bitonic sort, descending
  for (unsigned k2 = 2; k2 <= 1024; k2 <<= 1) {
    for (unsigned j = k2 >> 1; j > 0; j >>= 1) {
      unsigned i = tid, ixj = i ^ j;
      if (ixj > i) {
        unsigned long long a = keys[i], b = keys[ixj];
        bool sw = ((i & k2) == 0) ? (a < b) : (a > b);
        if (sw) { keys[i] = b; keys[ixj] = a; }
      }
      __syncthreads();
    }
  }
  if (tid < k) {
    unsigned long long key = keys[tid];
    unsigned u = (unsigned)(key >> 32);
    unsigned idx = ~((unsigned)key);
    float sc = funkey(u);
    float4 b = bsrc[idx];
    if (FINAL) {
      float* o = finalOut + ((size_t)img * 1000 + tid) * 5;
      o[0] = b.x; o[1] = b.y; o[2] = b.z; o[3] = b.w; o[4] = sc;
    } else {
      scoresOut[(size_t)img * ATOT_PER_IMG + c_AOFF[lvl] + tid] = sc;
      boxesOut[(size_t)img * ATOT_PER_IMG + c_AOFF[lvl] + tid] = b;
    }
  }
}

// ------------------------------ NMS ----------------------------------------
__global__ __launch_bounds__(256) void nms_matrix(
    const float4* __restrict__ allb, unsigned long long* __restrict__ supp) {
  int lvl = blockIdx.x, img = blockIdx.y, rb = blockIdx.z;
  int k = c_KLVL[lvl];
  int task = img * 5 + lvl;
  const float4* src = allb + (size_t)img * ATOT_PER_IMG + c_AOFF[lvl];
  __shared__ float4 bb[1000];
  __shared__ float ar[1000];
  for (int j = threadIdx.x; j < k; j += 256) {
    float4 b = src[j];
    bb[j] = b;
    ar[j] = __fmul_rn(__fsub_rn(b.z, b.x), __fsub_rn(b.w, b.y));
  }
  __syncthreads();
  int i = rb * 256 + threadIdx.x;
  if (i < k) {
    float4 bi = bb[i];
    float ai = ar[i];
    unsigned long long* row = supp + ((size_t)task * 1024 + i) * 16;
    int jw0 = i >> 6;
    for (int jw = 0; jw < jw0; jw++) row[jw] = 0ull;
    for (int jw = jw0; jw < 16; jw++) {
      unsigned long long bits = 0;
      int jbase = jw * 64;
      for (int jj = 0; jj < 64; jj++) {
        int j = jbase + jj;
        if (j > i && j < k) {
          float4 bj = bb[j];
          float ltx = fmaxf(bi.x, bj.x), lty = fmaxf(bi.y, bj.y);
          float rbx = fminf(bi.z, bj.z), rby = fminf(bi.w, bj.w);
          float wx = fmaxf(__fsub_rn(rbx, ltx), 0.f);
          float wy = fmaxf(__fsub_rn(rby, lty), 0.f);
          float inter = __fmul_rn(wx, wy);
          float den = __fadd_rn(__fsub_rn(__fadd_rn(ai, ar[j]), inter), 1e-9f);
          if (__fdiv_rn(inter, den) > 0.7f) bits |= 1ull << jj;
        }
      }
      row[jw] = bits;
    }
  }
}

__global__ __launch_bounds__(64) void nms_scan(
    const float* __restrict__ topS, const unsigned long long* __restrict__ supp,
    float* __restrict__ fscore) {
  int lvl = blockIdx.x, img = blockIdx.y;
  int k = c_KLVL[lvl];
  int task = img * 5 + lvl;
  int lane = threadIdx.x;
  const unsigned long long* base = supp + (size_t)task * 1024 * 16;
  unsigned long long rem = 0, keep = 0;  // lane l<16 holds 64-bit word l
  for (int b0 = 0; b0 < k; b0 += 16) {
    unsigned long long buf[16];
#pragma unroll
    for (int t = 0; t < 16; t++) {
      int i = b0 + t;
      buf[t] = (lane < 16 && i < k) ? base[(size_t)i * 16 + lane] : 0ull;
    }
#pragma unroll
    for (int t = 0; t < 16; t++) {
      int i = b0 + t;
      if (i >= k) break;
      int wi = i >> 6, bi = i & 63;
      unsigned long long rw = __shfl(rem, wi);
      if (!((rw >> bi) & 1ull)) {  // i survives: suppress its row
        rem |= buf[t];
        if (lane == wi) keep |= (1ull << bi);
      }
    }
  }
  const float* ts = topS + (size_t)img * ATOT_PER_IMG + c_AOFF[lvl];
  float* fs = fscore + (size_t)img * ATOT_PER_IMG + c_AOFF[lvl];
  for (int i = lane; i < k; i += 64) {
    int wi = i >> 6;
    unsigned long long kw = __shfl(keep, wi);
    fs[i] = ((kw >> (i & 63)) & 1ull) ? ts[i] : -1e9f;
  }
}

// ------------------------------ host ---------------------------------------
static Anch mkAnch(double size) {
  Anch a;
  const double R[3] = {0.5, 1.0, 2.0};
  for (int i = 0; i < 3; i++) {
    double w = size * sqrt(1.0 / R[i]);
    double h = size * sqrt(R[i]);
    a.cx1[i] = (float)(-w / 2.0);
    a.cy1[i] = (float)(-h / 2.0);
  }
  return a;
}

extern "C" void kernel_launch(void* const* d_in, const int* in_sizes, int n_in,
                              void* d_out, int out_size, void* d_ws,
                              size_t ws_size, hipStream_t stream) {
  (void)in_sizes; (void)n_in; (void)out_size; (void)ws_size;
  const float* feats[5] = {(const float*)d_in[0], (const float*)d_in[1],
                           (const float*)d_in[2], (const float*)d_in[3],
                           (const float*)d_in[4]};
  const float* conv_w = (const float*)d_in[5];
  const float* conv_b = (const float*)d_in[6];
  const float* cls_w  = (const float*)d_in[7];
  const float* cls_b  = (const float*)d_in[8];
  const float* bbox_w = (const float*)d_in[9];
  const float* bbox_b = (const float*)d_in[10];
  float* out = (float*)d_out;

  // workspace layout (floats), all 16B-aligned; total ~14.4 MB
  float* wsf = (float*)d_ws;
  float* Wt     = wsf;                      // 589824
  float* scores = Wt + 589824;              // 2*261888
  float* boxes  = scores + 2 * NTOT_PER_IMG;       // 2*261888*4
  float* topS   = boxes + (size_t)2 * NTOT_PER_IMG * 4;  // 2*4768
  float* allb   = topS + 2 * ATOT_PER_IMG;         // 2*4768*4
  float* fscore = allb + (size_t)2 * ATOT_PER_IMG * 4;   // 2*4768
  unsigned long long* supp =
      (unsigned long long*)(fscore + 2 * ATOT_PER_IMG);  // 10*1024*16 u64

  wtrans<<<dim3(144, 16), 256, 0, stream>>>(conv_w, Wt);

  const int Hs[5] = {256, 128, 64, 32, 16};
  const int STR[5] = {4, 8, 16, 32, 64};
  const double SZ[5] = {32, 64, 128, 256, 512};
  const int LOFF[5] = {0, 196608, 245760, 258048, 261120};

  for (int l = 0; l < 3; l++)
    conv_fused<64, 4><<<dim3(Hs[l] / 64, Hs[l], 2), 256, 0, stream>>>(
        feats[l], Wt, conv_b, cls_w, cls_b, bbox_w, bbox_b, scores,
        (float4*)boxes, Hs[l], STR[l], LOFF[l], mkAnch(SZ[l]));
  conv_fused<32, 2><<<dim3(1, 32, 2), 256, 0, stream>>>(
      feats[3], Wt, conv_b, cls_w, cls_b, bbox_w, bbox_b, scores,
      (float4*)boxes, 32, STR[3], LOFF[3], mkAnch(SZ[3]));
  conv_fused<16, 1><<<dim3(1, 16, 2), 256, 0, stream>>>(
      feats[4], Wt, conv_b, cls_w, cls_b, bbox_w, bbox_b, scores,
      (float4*)boxes, 16, STR[4], LOFF[4], mkAnch(SZ[4]));

  topk_kernel<false><<<dim3(5, 2), 1024, 0, stream>>>(
      scores, (const float4*)boxes, topS, (float4*)allb, nullptr);
  nms_matrix<<<dim3(5, 2, 4), 256, 0, stream>>>((const float4*)allb, supp);
  nms_scan<<<dim3(5, 2), 64, 0, stream>>>(topS, supp, fscore);
  topk_kernel<true><<<2, 1024, 0, stream>>>(
      fscore, (const float4*)allb, nullptr, nullptr, out);
}

// Round 2
// 5043.028 us; speedup vs baseline: 1.1297x; 1.1297x over previous
//
#include <hip/hip_runtime.h>
#include <cmath>

// ---------------------------------------------------------------------------
// RPN head on MI355X. fp32 throughout (order-sensitive output: top-k ranks and
// greedy-NMS decisions must match the fp32 reference bit-exactly; R1 measured
// absmax 0.0 with the canonical (ic,ky,kx) FMA chain — preserve that order).
//
// R2 changes (theory: conv was LDS-issue-bound on broadcast weight reads,
// occupancy capped at 2 blocks/CU by the 36KB weight tile):
//   - weights read directly from L2-resident Wt[k][256] into registers
//     (dwordx4), no weight staging, no weight ds_reads
//   - LDS 57.8KB -> 33.9KB, __launch_bounds__(256,4) -> 4 blocks/CU
//   - ic-chunk 4 -> 8 (half the barriers)
//   - all 5 levels + 2 images fused into ONE 2784-block dispatch so small
//     levels overlap level 0 instead of serializing at <128 blocks each
// ---------------------------------------------------------------------------

#define NTOT_PER_IMG 261888   // sum of H*W*3 over levels
#define ATOT_PER_IMG 4768     // 4*1000 + 768

__constant__ int c_NLVL[5] = {196608, 49152, 12288, 3072, 768};
__constant__ int c_KLVL[5] = {1000, 1000, 1000, 1000, 768};
__constant__ int c_LOFF[5] = {0, 196608, 245760, 258048, 261120};
__constant__ int c_AOFF[5] = {0, 1000, 2000, 3000, 4000};

struct Anch { float cx1[3]; float cy1[3]; };
struct ConvCfg { Anch an[5]; };

// ------------------------------ weight transpose ---------------------------
__global__ __launch_bounds__(256) void wtrans(const float* __restrict__ Wsrc,
                                              float* __restrict__ Wt) {
  __shared__ float T[16][17];
  int k0 = blockIdx.x * 16;   // 2304/16 = 144
  int o0 = blockIdx.y * 16;   // 256/16  = 16
  int i = threadIdx.x >> 4, j = threadIdx.x & 15;
  T[i][j] = Wsrc[(size_t)(o0 + i) * 2304 + (k0 + j)];
  __syncthreads();
  Wt[(size_t)(k0 + i) * 256 + (o0 + j)] = T[j][i];
}

// ------------------------------ fused conv body ----------------------------
// 256 threads; tile = PT pixels (one row segment) x 256 out-channels.
// Thread (tx=tid&15, ty=tid>>4): oc = ty*16+i (i<16), px = x0+tx*TP+p (p<TP).
// Weights come straight from global (L2); LDS holds only the X tile + heads.
template <int PT, int TP>
__device__ void conv_body(const float* __restrict__ feat,
                          const float4* __restrict__ Wt4,
                          const float* __restrict__ convb,
                          const float* __restrict__ clsw,
                          const float* __restrict__ clsb,
                          const float* __restrict__ bboxw,
                          const float* __restrict__ bboxb,
                          float* __restrict__ scoresOut,
                          float4* __restrict__ boxesOut, float* sm, int H,
                          int stride, int lvlOff, Anch an, int bx, int gy,
                          int img) {
  static_assert(PT == TP * 16, "tile");
  constexpr int ICB = 8;
  constexpr int XS = PT + 4;  // padded row stride, keeps rows 16B-aligned
  float* XsRed = sm;          // union: X tile (ICB*3*XS <= 1632) / Red (4096)
  float* CW = sm + 4096;      // [15][256] cls(3)+bbox(12) weights
  float* Cb = CW + 3840;      // [256] conv bias
  float* Bb = Cb + 256;       // [15] cls/bbox bias
  float* Red2 = Bb + 16;      // [16][17] reduced head values per pixel

  const int tid = threadIdx.x;
  const int tx = tid & 15;
  const int ty = tid >> 4;
  const int W = H;
  const int x0 = bx * PT;
  const float* f = feat + (size_t)img * 256 * H * W;

  for (int i = tid; i < 15 * 256; i += 256)
    CW[i] = (i < 768) ? clsw[i] : bboxw[i - 768];
  Cb[tid] = convb[tid];
  if (tid < 15) Bb[tid] = (tid < 3) ? clsb[tid] : bboxb[tid - 3];

  float acc[16][TP];
#pragma unroll
  for (int i = 0; i < 16; i++)
#pragma unroll
    for (int p = 0; p < TP; p++) acc[i][p] = 0.f;

  const float4* wbase = Wt4 + ty * 4;  // float4 row stride of Wt is 64

  for (int ic0 = 0; ic0 < 256; ic0 += ICB) {
    __syncthreads();  // protect X tile from previous chunk's readers
    for (int idx = tid; idx < ICB * 3 * (PT + 2); idx += 256) {
      int icr = idx / (3 * (PT + 2));
      int rem = idx - icr * 3 * (PT + 2);
      int ry = rem / (PT + 2);
      int xi = rem - ry * (PT + 2);
      int yy = gy + ry - 1;
      int xx = x0 + xi - 1;
      float v = 0.f;
      if (yy >= 0 && yy < H && xx >= 0 && xx < W)
        v = f[(size_t)(ic0 + icr) * H * W + (size_t)yy * W + xx];
      XsRed[(icr * 3 + ry) * XS + xi] = v;
    }
    __syncthreads();
#pragma unroll 1
    for (int icr = 0; icr < ICB; icr++) {
#pragma unroll
      for (int ky = 0; ky < 3; ky++) {
        float xv[TP + 2];
        const float* xrow = &XsRed[(icr * 3 + ky) * XS + tx * TP];
        if constexpr (TP == 4) {
          float4 x4 = *(const float4*)xrow;
          float2 x2 = *(const float2*)(xrow + 4);
          xv[0] = x4.x; xv[1] = x4.y; xv[2] = x4.z; xv[3] = x4.w;
          xv[4] = x2.x; xv[5] = x2.y;
        } else if constexpr (TP == 2) {
          float2 xa = *(const float2*)xrow;
          float2 xb = *(const float2*)(xrow + 2);
          xv[0] = xa.x; xv[1] = xa.y; xv[2] = xb.x; xv[3] = xb.y;
        } else {
          xv[0] = xrow[0]; xv[1] = xrow[1]; xv[2] = xrow[2];
        }
        const float4* wk = wbase + (size_t)((ic0 + icr) * 9 + ky * 3) * 64;
#pragma unroll
        for (int kx = 0; kx < 3; kx++) {
          float4 wa = wk[(size_t)kx * 64 + 0];
          float4 wb = wk[(size_t)kx * 64 + 1];
          float4 wc = wk[(size_t)kx * 64 + 2];
          float4 wd = wk[(size_t)kx * 64 + 3];
          float wv[16] = {wa.x, wa.y, wa.z, wa.w, wb.x, wb.y, wb.z, wb.w,
                          wc.x, wc.y, wc.z, wc.w, wd.x, wd.y, wd.z, wd.w};
#pragma unroll
          for (int i = 0; i < 16; i++)
#pragma unroll
            for (int p = 0; p < TP; p++)
              acc[i][p] = __builtin_fmaf(wv[i], xv[p + kx], acc[i][p]);
        }
      }
    }
  }
  __syncthreads();

  const float BCLIP = (float)4.135166556742356;  // log(1000/16)
  const size_t base = (size_t)img * NTOT_PER_IMG + lvlOff;
  float* Red = XsRed;  // 4096 floats, X tile dead now

  for (int p = 0; p < TP; p++) {
    float tv[16];
#pragma unroll
    for (int i = 0; i < 16; i++)
      tv[i] = fmaxf(acc[i][p] + Cb[ty * 16 + i], 0.f);
#pragma unroll
    for (int c = 0; c < 15; c++) {
      const float* wr = &CW[c * 256 + ty * 16];
      float s = 0.f;
#pragma unroll
      for (int i = 0; i < 16; i++) s += wr[i] * tv[i];
      Red[(tx * 16 + c) * 16 + ty] = s;
    }
    __syncthreads();
    if (tid < 240) {  // reduce across the 16 ty groups
      int px = tid / 15, c = tid - px * 15;
      const float* rr = &Red[(px * 16 + c) * 16];
      float s = 0.f;
#pragma unroll
      for (int t = 0; t < 16; t++) s += rr[t];
      Red2[px * 17 + c] = s + Bb[c];
    }
    __syncthreads();
    if (tid < 48) {  // decode: one (pixel, anchor) per thread
      int px = tid / 3, a = tid - px * 3;
      int gx = x0 + px * TP + p;
      float sc = Red2[px * 17 + a];
      float dxv = Red2[px * 17 + 3 + a * 4 + 0];
      float dyv = Red2[px * 17 + 3 + a * 4 + 1];
      float dwv = Red2[px * 17 + 3 + a * 4 + 2];
      float dhv = Red2[px * 17 + 3 + a * 4 + 3];
      float sx = (float)(gx * stride), sy = (float)(gy * stride);
      float x1 = __fadd_rn(sx, an.cx1[a]);
      float x2 = __fsub_rn(sx, an.cx1[a]);
      float y1 = __fadd_rn(sy, an.cy1[a]);
      float y2 = __fsub_rn(sy, an.cy1[a]);
      float wdt = __fadd_rn(__fsub_rn(x2, x1), 1.0f);
      float hgt = __fadd_rn(__fsub_rn(y2, y1), 1.0f);
      float ctx = __fadd_rn(x1, __fmul_rn(0.5f, wdt));
      float cty = __fadd_rn(y1, __fmul_rn(0.5f, hgt));
      float dw = fminf(dwv, BCLIP), dh = fminf(dhv, BCLIP);
      float pcx = __fadd_rn(__fmul_rn(dxv, wdt), ctx);
      float pcy = __fadd_rn(__fmul_rn(dyv, hgt), cty);
      float pw = __fmul_rn(expf(dw), wdt);
      float ph = __fmul_rn(expf(dh), hgt);
      float hw = __fmul_rn(0.5f, pw), hh = __fmul_rn(0.5f, ph);
      float bx1 = __fsub_rn(pcx, hw);
      float by1 = __fsub_rn(pcy, hh);
      float bx2 = __fsub_rn(__fadd_rn(pcx, hw), 1.0f);
      float by2 = __fsub_rn(__fadd_rn(pcy, hh), 1.0f);
      bx1 = fminf(fmaxf(bx1, 0.f), 1023.f);
      by1 = fminf(fmaxf(by1, 0.f), 1023.f);
      bx2 = fminf(fmaxf(bx2, 0.f), 1023.f);
      by2 = fminf(fmaxf(by2, 0.f), 1023.f);
      int g = gy * W + gx;
      size_t o = base + (size_t)g * 3 + a;
      scoresOut[o] = sc;
      boxesOut[o] = make_float4(bx1, by1, bx2, by2);
    }
    __syncthreads();
  }
}

// All 5 levels x 2 images in one dispatch; level decoded from blockIdx.x.
// Block ranges: L0 [0,2048) L1 [2048,2560) L2 [2560,2688) L3 [2688,2752)
// L4 [2752,2784). Level 0 first so big blocks start earliest.
__global__ __launch_bounds__(256, 4) void conv_all(
    const float* __restrict__ f0, const float* __restrict__ f1,
    const float* __restrict__ f2, const float* __restrict__ f3,
    const float* __restrict__ f4, const float* __restrict__ Wt,
    const float* __restrict__ convb, const float* __restrict__ clsw,
    const float* __restrict__ clsb, const float* __restrict__ bboxw,
    const float* __restrict__ bboxb, float* __restrict__ scoresOut,
    float4* __restrict__ boxesOut, ConvCfg cfg) {
  __shared__ __align__(16) float sm[8480];
  const float4* Wt4 = (const float4*)Wt;
  int b = blockIdx.x;
  if (b < 2048) {
    int img = b >> 10, r = b & 1023;
    conv_body<64, 4>(f0, Wt4, convb, clsw, clsb, bboxw, bboxb, scoresOut,
                     boxesOut, sm, 256, 4, 0, cfg.an[0], r & 3, r >> 2, img);
  } else if (b < 2560) {
    int r = b - 2048, img = r >> 8;
    r &= 255;
    conv_body<64, 4>(f1, Wt4, convb, clsw, clsb, bboxw, bboxb, scoresOut,
                     boxesOut, sm, 128, 8, 196608, cfg.an[1], r & 1, r >> 1,
                     img);
  } else if (b < 2688) {
    int r = b - 2560, img = r >> 6;
    r &= 63;
    conv_body<64, 4>(f2, Wt4, convb, clsw, clsb, bboxw, bboxb, scoresOut,
                     boxesOut, sm, 64, 16, 245760, cfg.an[2], 0, r, img);
  } else if (b < 2752) {
    int r = b - 2688, img = r >> 5;
    r &= 31;
    conv_body<32, 2>(f3, Wt4, convb, clsw, clsb, bboxw, bboxb, scoresOut,
                     boxesOut, sm, 32, 32, 258048, cfg.an[3], 0, r, img);
  } else {
    int r = b - 2752, img = r >> 4;
    r &= 15;
    conv_body<16, 1>(f4, Wt4, convb, clsw, clsb, bboxw, bboxb, scoresOut,
                     boxesOut, sm, 16, 64, 261120, cfg.an[4], 0, r, img);
  }
}

// ------------------------------ top-k --------------------------------------
__device__ __forceinline__ unsigned fkey(float f) {
  unsigned b = __float_as_uint(f);
  return (b & 0x80000000u) ? ~b : (b | 0x80000000u);
}
__device__ __forceinline__ float funkey(unsigned u) {
  unsigned b = (u & 0x80000000u) ? (u & 0x7fffffffu) : ~u;
  return __uint_as_float(b);
}

// Exact lax.top_k: value desc, index asc on ties. Radix-select the threshold,
// bisect an index cut for boundary ties, bitonic-sort packed (key, ~idx).
template <bool FINAL>
__global__ __launch_bounds__(1024) void topk_kernel(
    const float* __restrict__ scoresIn, const float4* __restrict__ boxesIn,
    float* __restrict__ scoresOut, float4* __restrict__ boxesOut,
    float* __restrict__ finalOut) {
  __shared__ unsigned long long keys[1024];
  __shared__ unsigned hist[256];
  __shared__ unsigned s_comm[4];
  int lvl = 0, img, N, k;
  const float* src;
  const float4* bsrc;
  if (FINAL) {
    img = blockIdx.x; N = ATOT_PER_IMG; k = 1000;
    src = scoresIn + (size_t)img * ATOT_PER_IMG;
    bsrc = boxesIn + (size_t)img * ATOT_PER_IMG;
  } else {
    lvl = blockIdx.x; img = blockIdx.y;
    N = c_NLVL[lvl]; k = c_KLVL[lvl];
    src = scoresIn + (size_t)img * NTOT_PER_IMG + c_LOFF[lvl];
    bsrc = boxesIn + (size_t)img * NTOT_PER_IMG + c_LOFF[lvl];
  }
  const int tid = threadIdx.x;

  unsigned pref = 0, pmask = 0, krem = (unsigned)k, cntT = 0;
  for (int pass = 3; pass >= 0; pass--) {
    int shift = pass * 8;
    if (tid < 256) hist[tid] = 0;
    __syncthreads();
    for (int i = tid; i < N; i += 1024) {
      unsigned u = fkey(src[i]);
      if ((u & pmask) == pref) atomicAdd(&hist[(u >> shift) & 255], 1u);
    }
    __syncthreads();
    if (tid == 0) {
      unsigned cum = 0;
      for (int d = 255; d >= 0; d--) {
        unsigned c = hist[d];
        if (cum + c >= krem) {
          s_comm[0] = krem - cum; s_comm[1] = c; s_comm[2] = (unsigned)d;
          break;
        }
        cum += c;
      }
    }
    __syncthreads();
    krem = s_comm[0]; cntT = s_comm[1];
    pref |= s_comm[2] << shift;
    pmask |= 0xFFu << shift;
    __syncthreads();
  }
  const unsigned T = pref, r = krem;
  unsigned m = (unsigned)N;
  if (r < cntT) {  // boundary ties: smallest r indices among {u == T}
    unsigned lo = 0, hi = (unsigned)N;
    while (lo < hi) {
      unsigned mid = (lo + hi) >> 1;
      if (tid == 0) s_comm[3] = 0;
      __syncthreads();
      for (unsigned i = tid; i < mid; i += 1024)
        if (fkey(src[i]) == T) atomicAdd(&s_comm[3], 1u);
      __syncthreads();
      unsigned c = s_comm[3];
      __syncthreads();
      if (c >= r) hi = mid; else lo = mid + 1;
    }
    m = lo;
  }
  if (tid == 0) s_comm[3] = 0;
  __syncthreads();
  for (int i = tid; i < N; i += 1024) {
    unsigned u = fkey(src[i]);
    if (u > T || (u == T && (unsigned)i < m)) {
      unsigned p = atomicAdd(&s_comm[3], 1u);
      if (p < 1024)
        keys[p] = ((unsigned long long)u << 32) | (unsigned)(~(unsigned)i);
    }
  }
  __syncthreads();
  if (tid >= k) keys[tid] = 0ull;  // pad; sorts to the end
  __syncthreads();
  // bitonic sort, descending
  for (unsigned k2 = 2; k2 <= 1024; k2 <<= 1) {
    for (unsigned j = k2 >> 1; j > 0; j >>= 1) {
      unsigned i = tid, ixj = i ^ j;
      if (ixj > i) {
        unsigned long long a = keys[i], b = keys[ixj];
        bool sw = ((i & k2) == 0) ? (a < b) : (a > b);
        if (sw) { keys[i] = b; keys[ixj] = a; }
      }
      __syncthreads();
    }
  }
  if (tid < k) {
    unsigned long long key = keys[tid];
    unsigned u = (unsigned)(key >> 32);
    unsigned idx = ~((unsigned)key);
    float sc = funkey(u);
    float4 b = bsrc[idx];
    if (FINAL) {
      float* o = finalOut + ((size_t)img * 1000 + tid) * 5;
      o[0] = b.x; o[1] = b.y; o[2] = b.z; o[3] = b.w; o[4] = sc;
    } else {
      scoresOut[(size_t)img * ATOT_PER_IMG + c_AOFF[lvl] + tid] = sc;
      boxesOut[(size_t)img * ATOT_PER_IMG + c_AOFF[lvl] + tid] = b;
    }
  }
}

// ------------------------------ NMS ----------------------------------------
__global__ __launch_bounds__(256) void nms_matrix(
    const float4* __restrict__ allb, unsigned long long* __restrict__ supp) {
  int lvl = blockIdx.x, img = blockIdx.y, rb = blockIdx.z;
  int k = c_KLVL[lvl];
  int task = img * 5 + lvl;
  const float4* src = allb + (size_t)img * ATOT_PER_IMG + c_AOFF[lvl];
  __shared__ float4 bb[1000];
  __shared__ float ar[1000];
  for (int j = threadIdx.x; j < k; j += 256) {
    float4 b = src[j];
    bb[j] = b;
    ar[j] = __fmul_rn(__fsub_rn(b.z, b.x), __fsub_rn(b.w, b.y));
  }
  __syncthreads();
  int i = rb * 256 + threadIdx.x;
  if (i < k) {
    float4 bi = bb[i];
    float ai = ar[i];
    unsigned long long* row = supp + ((size_t)task * 1024 + i) * 16;
    int jw0 = i >> 6;
    for (int jw = 0; jw < jw0; jw++) row[jw] = 0ull;
    for (int jw = jw0; jw < 16; jw++) {
      unsigned long long bits = 0;
      int jbase = jw * 64;
      for (int jj = 0; jj < 64; jj++) {
        int j = jbase + jj;
        if (j > i && j < k) {
          float4 bj = bb[j];
          float ltx = fmaxf(bi.x, bj.x), lty = fmaxf(bi.y, bj.y);
          float rbx = fminf(bi.z, bj.z), rby = fminf(bi.w, bj.w);
          float wx = fmaxf(__fsub_rn(rbx, ltx), 0.f);
          float wy = fmaxf(__fsub_rn(rby, lty), 0.f);
          float inter = __fmul_rn(wx, wy);
          float den = __fadd_rn(__fsub_rn(__fadd_rn(ai, ar[j]), inter), 1e-9f);
          if (__fdiv_rn(inter, den) > 0.7f) bits |= 1ull << jj;
        }
      }
      row[jw] = bits;
    }
  }
}

__global__ __launch_bounds__(64) void nms_scan(
    const float* __restrict__ topS, const unsigned long long* __restrict__ supp,
    float* __restrict__ fscore) {
  int lvl = blockIdx.x, img = blockIdx.y;
  int k = c_KLVL[lvl];
  int task = img * 5 + lvl;
  int lane = threadIdx.x;
  const unsigned long long* base = supp + (size_t)task * 1024 * 16;
  unsigned long long rem = 0, keep = 0;  // lane l<16 holds 64-bit word l
  for (int b0 = 0; b0 < k; b0 += 16) {
    unsigned long long buf[16];
#pragma unroll
    for (int t = 0; t < 16; t++) {
      int i = b0 + t;
      buf[t] = (lane < 16 && i < k) ? base[(size_t)i * 16 + lane] : 0ull;
    }
#pragma unroll
    for (int t = 0; t < 16; t++) {
      int i = b0 + t;
      if (i >= k) break;
      int wi = i >> 6, bi = i & 63;
      unsigned long long rw = __shfl(rem, wi);
      if (!((rw >> bi) & 1ull)) {  // i survives: suppress its row
        rem |= buf[t];
        if (lane == wi) keep |= (1ull << bi);
      }
    }
  }
  const float* ts = topS + (size_t)img * ATOT_PER_IMG + c_AOFF[lvl];
  float* fs = fscore + (size_t)img * ATOT_PER_IMG + c_AOFF[lvl];
  for (int i = lane; i < k; i += 64) {
    int wi = i >> 6;
    unsigned long long kw = __shfl(keep, wi);
    fs[i] = ((kw >> (i & 63)) & 1ull) ? ts[i] : -1e9f;
  }
}

// ------------------------------ host ---------------------------------------
static Anch mkAnch(double size) {
  Anch a;
  const double R[3] = {0.5, 1.0, 2.0};
  for (int i = 0; i < 3; i++) {
    double w = size * sqrt(1.0 / R[i]);
    double h = size * sqrt(R[i]);
    a.cx1[i] = (float)(-w / 2.0);
    a.cy1[i] = (float)(-h / 2.0);
  }
  return a;
}

extern "C" void kernel_launch(void* const* d_in, const int* in_sizes, int n_in,
                              void* d_out, int out_size, void* d_ws,
                              size_t ws_size, hipStream_t stream) {
  (void)in_sizes; (void)n_in; (void)out_size; (void)ws_size;
  const float* f0 = (const float*)d_in[0];
  const float* f1 = (const float*)d_in[1];
  const float* f2 = (const float*)d_in[2];
  const float* f3 = (const float*)d_in[3];
  const float* f4 = (const float*)d_in[4];
  const float* conv_w = (const float*)d_in[5];
  const float* conv_b = (const float*)d_in[6];
  const float* cls_w  = (const float*)d_in[7];
  const float* cls_b  = (const float*)d_in[8];
  const float* bbox_w = (const float*)d_in[9];
  const float* bbox_b = (const float*)d_in[10];
  float* out = (float*)d_out;

  // workspace layout (floats), all 16B-aligned; total ~14.4 MB
  float* wsf = (float*)d_ws;
  float* Wt     = wsf;                      // 589824
  float* scores = Wt + 589824;              // 2*261888
  float* boxes  = scores + 2 * NTOT_PER_IMG;       // 2*261888*4
  float* topS   = boxes + (size_t)2 * NTOT_PER_IMG * 4;  // 2*4768
  float* allb   = topS + 2 * ATOT_PER_IMG;         // 2*4768*4
  float* fscore = allb + (size_t)2 * ATOT_PER_IMG * 4;   // 2*4768
  unsigned long long* supp =
      (unsigned long long*)(fscore + 2 * ATOT_PER_IMG);  // 10*1024*16 u64

  wtrans<<<dim3(144, 16), 256, 0, stream>>>(conv_w, Wt);

  ConvCfg cfg;
  const double SZ[5] = {32, 64, 128, 256, 512};
  for (int l = 0; l < 5; l++) cfg.an[l] = mkAnch(SZ[l]);

  conv_all<<<2784, 256, 0, stream>>>(f0, f1, f2, f3, f4, Wt, conv_b, cls_w,
                                     cls_b, bbox_w, bbox_b, scores,
                                     (float4*)boxes, cfg);

  topk_kernel<false><<<dim3(5, 2), 1024, 0, stream>>>(
      scores, (const float4*)boxes, topS, (float4*)allb, nullptr);
  nms_matrix<<<dim3(5, 2, 4), 256, 0, stream>>>((const float4*)allb, supp);
  nms_scan<<<dim3(5, 2), 64, 0, stream>>>(topS, supp, fscore);
  topk_kernel<true><<<2, 1024, 0, stream>>>(
      fscore, (const float4*)allb, nullptr, nullptr, out);
}

// Round 3
// 3827.481 us; speedup vs baseline: 1.4884x; 1.3176x over previous
//
#include <hip/hip_runtime.h>
#include <cmath>

// ---------------------------------------------------------------------------
// RPN head on MI355X. fp32 throughout; conv FMA chain order (ic,ky,kx asc,
// fmaf(w,x,acc)) and the head's 16x16 two-level reduction are bit-exact vs
// the np reference (R1/R2 measured absmax 0.0) — preserve both exactly.
//
// R3 structure (theory: R2 was vmcnt-stalled on per-lane L2 weight loads,
// 40% of VALU slots were address/unpack overhead):
//   lane = oc (64 oc/wave, 4 waves = 256 oc), regs = 16 px (acc[16]).
//   X row segments are wave-uniform -> scalar s_load into SGPRs (halo zeros
//   materialized via uniform branches; scalar pipe co-issues with VALU).
//   Weights: 3 coalesced dwords per lane per (ic,ky) (256B/wave, L2-hot).
//   Main loop: 48 v_fmac per (ic,ky), zero LDS, zero barriers.
//   Epilogue: t -> LDS [16px][256oc], head dots from global (L1-hot 15KB),
//   decode. LDS 17.5KB, __launch_bounds__(256,6).
//   All 10912 blocks have identical FLOP count (16px x 256oc x 2304k).
// ---------------------------------------------------------------------------

#define NTOT_PER_IMG 261888   // sum of H*W*3 over levels
#define ATOT_PER_IMG 4768     // 4*1000 + 768

__constant__ int c_NLVL[5] = {196608, 49152, 12288, 3072, 768};
__constant__ int c_KLVL[5] = {1000, 1000, 1000, 1000, 768};
__constant__ int c_LOFF[5] = {0, 196608, 245760, 258048, 261120};
__constant__ int c_AOFF[5] = {0, 1000, 2000, 3000, 4000};

struct Anch { float cx1[3]; float cy1[3]; };
struct ConvCfg { Anch an[5]; };

// ------------------------------ weight transpose ---------------------------
__global__ __launch_bounds__(256) void wtrans(const float* __restrict__ Wsrc,
                                              float* __restrict__ Wt) {
  __shared__ float T[16][17];
  int k0 = blockIdx.x * 16;   // 2304/16 = 144
  int o0 = blockIdx.y * 16;   // 256/16  = 16
  int i = threadIdx.x >> 4, j = threadIdx.x & 15;
  T[i][j] = Wsrc[(size_t)(o0 + i) * 2304 + (k0 + j)];
  __syncthreads();
  Wt[(size_t)(k0 + i) * 256 + (o0 + j)] = T[j][i];
}

// ------------------------------ fused conv ---------------------------------
// One block = 16 consecutive px of one output row x all 256 oc.
__global__ __launch_bounds__(256, 6) void conv_all(
    const float* __restrict__ f0, const float* __restrict__ f1,
    const float* __restrict__ f2, const float* __restrict__ f3,
    const float* __restrict__ f4, const float* __restrict__ Wt,
    const float* __restrict__ convb, const float* __restrict__ clsw,
    const float* __restrict__ clsb, const float* __restrict__ bboxw,
    const float* __restrict__ bboxb, float* __restrict__ scoresOut,
    float4* __restrict__ boxesOut, ConvCfg cfg) {
  __shared__ __align__(16) float sm[4096 + 272];  // t[16][256] + Red2[16][17]
  float* tl = sm;
  float* Red2 = sm + 4096;

  // ---- decode level / image / tile from blockIdx ----
  int b = blockIdx.x;
  const float* feat;
  int lvl, img, gy, bx, H, stride, lvlOff;
  if (b < 8192) {
    lvl = 0; feat = f0; H = 256; stride = 4; lvlOff = 0;
    img = b >> 12; int r = b & 4095; gy = r >> 4; bx = r & 15;
  } else if (b < 10240) {
    lvl = 1; feat = f1; H = 128; stride = 8; lvlOff = 196608;
    int rb = b - 8192; img = rb >> 10; int r = rb & 1023; gy = r >> 3; bx = r & 7;
  } else if (b < 10752) {
    lvl = 2; feat = f2; H = 64; stride = 16; lvlOff = 245760;
    int rb = b - 10240; img = rb >> 8; int r = rb & 255; gy = r >> 2; bx = r & 3;
  } else if (b < 10880) {
    lvl = 3; feat = f3; H = 32; stride = 32; lvlOff = 258048;
    int rb = b - 10752; img = rb >> 6; int r = rb & 63; gy = r >> 1; bx = r & 1;
  } else {
    lvl = 4; feat = f4; H = 16; stride = 64; lvlOff = 261120;
    int rb = b - 10880; img = rb >> 4; gy = rb & 15; bx = 0;
  }
  const int W = H;
  const int x0 = bx * 16;
  const Anch an = cfg.an[lvl];

  const int tid = threadIdx.x;
  const int lane = tid & 63;
  const int wav = __builtin_amdgcn_readfirstlane(tid >> 6);
  const int oc = wav * 64 + lane;

  const float* f = feat + (size_t)img * 256 * H * W;

  float acc[16];
#pragma unroll
  for (int p = 0; p < 16; p++) acc[p] = 0.f;

  const bool leftEdge = (x0 == 0);
  const bool rightEdge = (x0 + 16 >= W);

#pragma unroll 1
  for (int ic = 0; ic < 256; ic++) {
    const float* frow0 = f + (size_t)ic * H * W;
#pragma unroll
    for (int ky = 0; ky < 3; ky++) {
      int row = gy + ky - 1;
      float a[18];
      if (row >= 0 && row < H) {            // wave-uniform branch
        const float* rp = frow0 + (size_t)row * W + x0;
#pragma unroll
        for (int j = 0; j < 16; j++) a[j + 1] = rp[j];   // uniform -> s_load
        a[0] = leftEdge ? 0.f : rp[-1];
        a[17] = rightEdge ? 0.f : rp[16];
      } else {
#pragma unroll
        for (int j = 0; j < 18; j++) a[j] = 0.f;
      }
      const float* wrow = Wt + (size_t)(ic * 9 + ky * 3) * 256 + oc;
      float w0 = wrow[0];
      float w1 = wrow[256];
      float w2 = wrow[512];
      // chain order per px: kx=0,1,2 ascending (matches reference bit-exact)
#pragma unroll
      for (int p = 0; p < 16; p++) acc[p] = __builtin_fmaf(w0, a[p], acc[p]);
#pragma unroll
      for (int p = 0; p < 16; p++) acc[p] = __builtin_fmaf(w1, a[p + 1], acc[p]);
#pragma unroll
      for (int p = 0; p < 16; p++) acc[p] = __builtin_fmaf(w2, a[p + 2], acc[p]);
    }
  }

  // ---- epilogue: bias + relu -> LDS t[px][oc] ----
  float cb = convb[oc];
#pragma unroll
  for (int p = 0; p < 16; p++)
    tl[p * 256 + oc] = fmaxf(acc[p] + cb, 0.f);
  __syncthreads();

  // ---- heads: per (px, c) dot over 256 oc in 16x16 two-level order ----
  if (tid < 240) {
    int px = tid / 15, c = tid - px * 15;
    const float* wr0 = (c < 3) ? (clsw + c * 256) : (bboxw + (c - 3) * 256);
    float bb = (c < 3) ? clsb[c] : bboxb[c - 3];
    const float* trow = &tl[px * 256];
    float tot = 0.f;
#pragma unroll
    for (int g = 0; g < 16; g++) {
      const float* wr = wr0 + g * 16;
      const float* tr = trow + g * 16;
      float s = 0.f;
#pragma unroll
      for (int i = 0; i < 16; i++) s += wr[i] * tr[i];
      tot += s;
    }
    Red2[px * 17 + c] = tot + bb;
  }
  __syncthreads();

  // ---- decode: one (pixel, anchor) per thread ----
  const float BCLIP = (float)4.135166556742356;  // log(1000/16)
  const size_t base = (size_t)img * NTOT_PER_IMG + lvlOff;
  if (tid < 48) {
    int px = tid / 3, a = tid - px * 3;
    int gx = x0 + px;
    float sc = Red2[px * 17 + a];
    float dxv = Red2[px * 17 + 3 + a * 4 + 0];
    float dyv = Red2[px * 17 + 3 + a * 4 + 1];
    float dwv = Red2[px * 17 + 3 + a * 4 + 2];
    float dhv = Red2[px * 17 + 3 + a * 4 + 3];
    float sx = (float)(gx * stride), sy = (float)(gy * stride);
    float x1 = __fadd_rn(sx, an.cx1[a]);
    float x2 = __fsub_rn(sx, an.cx1[a]);
    float y1 = __fadd_rn(sy, an.cy1[a]);
    float y2 = __fsub_rn(sy, an.cy1[a]);
    float wdt = __fadd_rn(__fsub_rn(x2, x1), 1.0f);
    float hgt = __fadd_rn(__fsub_rn(y2, y1), 1.0f);
    float ctx = __fadd_rn(x1, __fmul_rn(0.5f, wdt));
    float cty = __fadd_rn(y1, __fmul_rn(0.5f, hgt));
    float dw = fminf(dwv, BCLIP), dh = fminf(dhv, BCLIP);
    float pcx = __fadd_rn(__fmul_rn(dxv, wdt), ctx);
    float pcy = __fadd_rn(__fmul_rn(dyv, hgt), cty);
    float pw = __fmul_rn(expf(dw), wdt);
    float ph = __fmul_rn(expf(dh), hgt);
    float hw = __fmul_rn(0.5f, pw), hh = __fmul_rn(0.5f, ph);
    float bx1 = __fsub_rn(pcx, hw);
    float by1 = __fsub_rn(pcy, hh);
    float bx2 = __fsub_rn(__fadd_rn(pcx, hw), 1.0f);
    float by2 = __fsub_rn(__fadd_rn(pcy, hh), 1.0f);
    bx1 = fminf(fmaxf(bx1, 0.f), 1023.f);
    by1 = fminf(fmaxf(by1, 0.f), 1023.f);
    bx2 = fminf(fmaxf(bx2, 0.f), 1023.f);
    by2 = fminf(fmaxf(by2, 0.f), 1023.f);
    int g = gy * W + gx;
    size_t o = base + (size_t)g * 3 + a;
    scoresOut[o] = sc;
    boxesOut[o] = make_float4(bx1, by1, bx2, by2);
  }
}

// ------------------------------ top-k --------------------------------------
__device__ __forceinline__ unsigned fkey(float f) {
  unsigned b = __float_as_uint(f);
  return (b & 0x80000000u) ? ~b : (b | 0x80000000u);
}
__device__ __forceinline__ float funkey(unsigned u) {
  unsigned b = (u & 0x80000000u) ? (u & 0x7fffffffu) : ~u;
  return __uint_as_float(b);
}

// Exact lax.top_k: value desc, index asc on ties. Radix-select the threshold,
// bisect an index cut for boundary ties, bitonic-sort packed (key, ~idx).
template <bool FINAL>
__global__ __launch_bounds__(1024) void topk_kernel(
    const float* __restrict__ scoresIn, const float4* __restrict__ boxesIn,
    float* __restrict__ scoresOut, float4* __restrict__ boxesOut,
    float* __restrict__ finalOut) {
  __shared__ unsigned long long keys[1024];
  __shared__ unsigned hist[256];
  __shared__ unsigned s_comm[4];
  int lvl = 0, img, N, k;
  const float* src;
  const float4* bsrc;
  if (FINAL) {
    img = blockIdx.x; N = ATOT_PER_IMG; k = 1000;
    src = scoresIn + (size_t)img * ATOT_PER_IMG;
    bsrc = boxesIn + (size_t)img * ATOT_PER_IMG;
  } else {
    lvl = blockIdx.x; img = blockIdx.y;
    N = c_NLVL[lvl]; k = c_KLVL[lvl];
    src = scoresIn + (size_t)img * NTOT_PER_IMG + c_LOFF[lvl];
    bsrc = boxesIn + (size_t)img * NTOT_PER_IMG + c_LOFF[lvl];
  }
  const int tid = threadIdx.x;

  unsigned pref = 0, pmask = 0, krem = (unsigned)k, cntT = 0;
  for (int pass = 3; pass >= 0; pass--) {
    int shift = pass * 8;
    if (tid < 256) hist[tid] = 0;
    __syncthreads();
    for (int i = tid; i < N; i += 1024) {
      unsigned u = fkey(src[i]);
      if ((u & pmask) == pref) atomicAdd(&hist[(u >> shift) & 255], 1u);
    }
    __syncthreads();
    if (tid == 0) {
      unsigned cum = 0;
      for (int d = 255; d >= 0; d--) {
        unsigned c = hist[d];
        if (cum + c >= krem) {
          s_comm[0] = krem - cum; s_comm[1] = c; s_comm[2] = (unsigned)d;
          break;
        }
        cum += c;
      }
    }
    __syncthreads();
    krem = s_comm[0]; cntT = s_comm[1];
    pref |= s_comm[2] << shift;
    pmask |= 0xFFu << shift;
    __syncthreads();
  }
  const unsigned T = pref, r = krem;
  unsigned m = (unsigned)N;
  if (r < cntT) {  // boundary ties: smallest r indices among {u == T}
    unsigned lo = 0, hi = (unsigned)N;
    while (lo < hi) {
      unsigned mid = (lo + hi) >> 1;
      if (tid == 0) s_comm[3] = 0;
      __syncthreads();
      for (unsigned i = tid; i < mid; i += 1024)
        if (fkey(src[i]) == T) atomicAdd(&s_comm[3], 1u);
      __syncthreads();
      unsigned c = s_comm[3];
      __syncthreads();
      if (c >= r) hi = mid; else lo = mid + 1;
    }
    m = lo;
  }
  if (tid == 0) s_comm[3] = 0;
  __syncthreads();
  for (int i = tid; i < N; i += 1024) {
    unsigned u = fkey(src[i]);
    if (u > T || (u == T && (unsigned)i < m)) {
      unsigned p = atomicAdd(&s_comm[3], 1u);
      if (p < 1024)
        keys[p] = ((unsigned long long)u << 32) | (unsigned)(~(unsigned)i);
    }
  }
  __syncthreads();
  if (tid >= k) keys[tid] = 0ull;  // pad; sorts to the end
  __syncthreads();
  // bitonic sort, descending
  for (unsigned k2 = 2; k2 <= 1024; k2 <<= 1) {
    for (unsigned j = k2 >> 1; j > 0; j >>= 1) {
      unsigned i = tid, ixj = i ^ j;
      if (ixj > i) {
        unsigned long long a = keys[i], b = keys[ixj];
        bool sw = ((i & k2) == 0) ? (a < b) : (a > b);
        if (sw) { keys[i] = b; keys[ixj] = a; }
      }
      __syncthreads();
    }
  }
  if (tid < k) {
    unsigned long long key = keys[tid];
    unsigned u = (unsigned)(key >> 32);
    unsigned idx = ~((unsigned)key);
    float sc = funkey(u);
    float4 b = bsrc[idx];
    if (FINAL) {
      float* o = finalOut + ((size_t)img * 1000 + tid) * 5;
      o[0] = b.x; o[1] = b.y; o[2] = b.z; o[3] = b.w; o[4] = sc;
    } else {
      scoresOut[(size_t)img * ATOT_PER_IMG + c_AOFF[lvl] + tid] = sc;
      boxesOut[(size_t)img * ATOT_PER_IMG + c_AOFF[lvl] + tid] = b;
    }
  }
}

// ------------------------------ NMS ----------------------------------------
__global__ __launch_bounds__(256) void nms_matrix(
    const float4* __restrict__ allb, unsigned long long* __restrict__ supp) {
  int lvl = blockIdx.x, img = blockIdx.y, rb = blockIdx.z;
  int k = c_KLVL[lvl];
  int task = img * 5 + lvl;
  const float4* src = allb + (size_t)img * ATOT_PER_IMG + c_AOFF[lvl];
  __shared__ float4 bb[1000];
  __shared__ float ar[1000];
  for (int j = threadIdx.x; j < k; j += 256) {
    float4 b = src[j];
    bb[j] = b;
    ar[j] = __fmul_rn(__fsub_rn(b.z, b.x), __fsub_rn(b.w, b.y));
  }
  __syncthreads();
  int i = rb * 256 + threadIdx.x;
  if (i < k) {
    float4 bi = bb[i];
    float ai = ar[i];
    unsigned long long* row = supp + ((size_t)task * 1024 + i) * 16;
    int jw0 = i >> 6;
    for (int jw = 0; jw < jw0; jw++) row[jw] = 0ull;
    for (int jw = jw0; jw < 16; jw++) {
      unsigned long long bits = 0;
      int jbase = jw * 64;
      for (int jj = 0; jj < 64; jj++) {
        int j = jbase + jj;
        if (j > i && j < k) {
          float4 bj = bb[j];
          float ltx = fmaxf(bi.x, bj.x), lty = fmaxf(bi.y, bj.y);
          float rbx = fminf(bi.z, bj.z), rby = fminf(bi.w, bj.w);
          float wx = fmaxf(__fsub_rn(rbx, ltx), 0.f);
          float wy = fmaxf(__fsub_rn(rby, lty), 0.f);
          float inter = __fmul_rn(wx, wy);
          float den = __fadd_rn(__fsub_rn(__fadd_rn(ai, ar[j]), inter), 1e-9f);
          if (__fdiv_rn(inter, den) > 0.7f) bits |= 1ull << jj;
        }
      }
      row[jw] = bits;
    }
  }
}

__global__ __launch_bounds__(64) void nms_scan(
    const float* __restrict__ topS, const unsigned long long* __restrict__ supp,
    float* __restrict__ fscore) {
  int lvl = blockIdx.x, img = blockIdx.y;
  int k = c_KLVL[lvl];
  int task = img * 5 + lvl;
  int lane = threadIdx.x;
  const unsigned long long* base = supp + (size_t)task * 1024 * 16;
  unsigned long long rem = 0, keep = 0;  // lane l<16 holds 64-bit word l
  for (int b0 = 0; b0 < k; b0 += 16) {
    unsigned long long buf[16];
#pragma unroll
    for (int t = 0; t < 16; t++) {
      int i = b0 + t;
      buf[t] = (lane < 16 && i < k) ? base[(size_t)i * 16 + lane] : 0ull;
    }
#pragma unroll
    for (int t = 0; t < 16; t++) {
      int i = b0 + t;
      if (i >= k) break;
      int wi = i >> 6, bi = i & 63;
      unsigned long long rw = __shfl(rem, wi);
      if (!((rw >> bi) & 1ull)) {  // i survives: suppress its row
        rem |= buf[t];
        if (lane == wi) keep |= (1ull << bi);
      }
    }
  }
  const float* ts = topS + (size_t)img * ATOT_PER_IMG + c_AOFF[lvl];
  float* fs = fscore + (size_t)img * ATOT_PER_IMG + c_AOFF[lvl];
  for (int i = lane; i < k; i += 64) {
    int wi = i >> 6;
    unsigned long long kw = __shfl(keep, wi);
    fs[i] = ((kw >> (i & 63)) & 1ull) ? ts[i] : -1e9f;
  }
}

// ------------------------------ host ---------------------------------------
static Anch mkAnch(double size) {
  Anch a;
  const double R[3] = {0.5, 1.0, 2.0};
  for (int i = 0; i < 3; i++) {
    double w = size * sqrt(1.0 / R[i]);
    double h = size * sqrt(R[i]);
    a.cx1[i] = (float)(-w / 2.0);
    a.cy1[i] = (float)(-h / 2.0);
  }
  return a;
}

extern "C" void kernel_launch(void* const* d_in, const int* in_sizes, int n_in,
                              void* d_out, int out_size, void* d_ws,
                              size_t ws_size, hipStream_t stream) {
  (void)in_sizes; (void)n_in; (void)out_size; (void)ws_size;
  const float* f0 = (const float*)d_in[0];
  const float* f1 = (const float*)d_in[1];
  const float* f2 = (const float*)d_in[2];
  const float* f3 = (const float*)d_in[3];
  const float* f4 = (const float*)d_in[4];
  const float* conv_w = (const float*)d_in[5];
  const float* conv_b = (const float*)d_in[6];
  const float* cls_w  = (const float*)d_in[7];
  const float* cls_b  = (const float*)d_in[8];
  const float* bbox_w = (const float*)d_in[9];
  const float* bbox_b = (const float*)d_in[10];
  float* out = (float*)d_out;

  // workspace layout (floats), all 16B-aligned; total ~14.4 MB
  float* wsf = (float*)d_ws;
  float* Wt     = wsf;                      // 589824
  float* scores = Wt + 589824;              // 2*261888
  float* boxes  = scores + 2 * NTOT_PER_IMG;       // 2*261888*4
  float* topS   = boxes + (size_t)2 * NTOT_PER_IMG * 4;  // 2*4768
  float* allb   = topS + 2 * ATOT_PER_IMG;         // 2*4768*4
  float* fscore = allb + (size_t)2 * ATOT_PER_IMG * 4;   // 2*4768
  unsigned long long* supp =
      (unsigned long long*)(fscore + 2 * ATOT_PER_IMG);  // 10*1024*16 u64

  wtrans<<<dim3(144, 16), 256, 0, stream>>>(conv_w, Wt);

  ConvCfg cfg;
  const double SZ[5] = {32, 64, 128, 256, 512};
  for (int l = 0; l < 5; l++) cfg.an[l] = mkAnch(SZ[l]);

  conv_all<<<10912, 256, 0, stream>>>(f0, f1, f2, f3, f4, Wt, conv_b, cls_w,
                                      cls_b, bbox_w, bbox_b, scores,
                                      (float4*)boxes, cfg);

  topk_kernel<false><<<dim3(5, 2), 1024, 0, stream>>>(
      scores, (const float4*)boxes, topS, (float4*)allb, nullptr);
  nms_matrix<<<dim3(5, 2, 4), 256, 0, stream>>>((const float4*)allb, supp);
  nms_scan<<<dim3(5, 2), 64, 0, stream>>>(topS, supp, fscore);
  topk_kernel<true><<<2, 1024, 0, stream>>>(
      fscore, (const float4*)allb, nullptr, nullptr, out);
}